// Round 24
// baseline (275.282 us; speedup 1.0000x reference)
//
#include <hip/hip_runtime.h>
#include <hip/hip_bf16.h>

typedef __hip_bfloat16 bf16;
typedef __attribute__((ext_vector_type(8))) __bf16 bf16x8;
typedef __attribute__((ext_vector_type(4))) float f32x4;
typedef __attribute__((ext_vector_type(16))) float f32x16;
typedef __attribute__((ext_vector_type(8))) short s16x8;
typedef __attribute__((ext_vector_type(4))) unsigned u32x4;

#define B_    8
#define S_    1024
#define H_    16
#define D_    128
#define HID_  2048
#define NQKV_ 2304
#define T_    8192

__device__ __forceinline__ void gload_lds16(const void* g, void* l) {
  __builtin_amdgcn_global_load_lds((const __attribute__((address_space(1))) void*)g,
                                   (__attribute__((address_space(3))) void*)l, 16, 0, 0);
}

__device__ __forceinline__ unsigned pack_bf16(float lo, float hi) {
  return ((unsigned)__bfloat16_as_ushort(__float2bfloat16(hi)) << 16) |
         (unsigned)__bfloat16_as_ushort(__float2bfloat16(lo));
}

// ---------------- cast fp32 -> bf16, 8 elems/thread ----------------
__global__ void cast_bf16_kernel(const float* __restrict__ src, bf16* __restrict__ dst, int n8) {
  const int i = blockIdx.x * 256 + threadIdx.x;
  if (i >= n8) return;
  const float4 a = ((const float4*)src)[2 * i];
  const float4 b = ((const float4*)src)[2 * i + 1];
  s16x8 o;
  o[0] = (short)__bfloat16_as_ushort(__float2bfloat16(a.x));
  o[1] = (short)__bfloat16_as_ushort(__float2bfloat16(a.y));
  o[2] = (short)__bfloat16_as_ushort(__float2bfloat16(a.z));
  o[3] = (short)__bfloat16_as_ushort(__float2bfloat16(a.w));
  o[4] = (short)__bfloat16_as_ushort(__float2bfloat16(b.x));
  o[5] = (short)__bfloat16_as_ushort(__float2bfloat16(b.y));
  o[6] = (short)__bfloat16_as_ushort(__float2bfloat16(b.z));
  o[7] = (short)__bfloat16_as_ushort(__float2bfloat16(b.w));
  ((s16x8*)dst)[i] = o;
}

// ------------- transpose + cast: src (R x C) f32 -> dst (C x R) bf16 -------------
__global__ void transpose_cast_kernel(const float* __restrict__ src, bf16* __restrict__ dst,
                                      int R, int C) {
  __shared__ float tile[32][33];
  const int tx = threadIdx.x & 31, ty = threadIdx.x >> 5;
  const int rt = blockIdx.y * 32, ct = blockIdx.x * 32;
#pragma unroll
  for (int k = 0; k < 4; ++k)
    tile[ty + 8 * k][tx] = src[(size_t)(rt + ty + 8 * k) * C + ct + tx];
  __syncthreads();
#pragma unroll
  for (int k = 0; k < 4; ++k)
    dst[(size_t)(ct + ty + 8 * k) * R + rt + tx] = __float2bfloat16(tile[tx][ty + 8 * k]);
}

// ------------- V transpose: QKV V-cols -> Vt[b][d][k] bf16 -------------
__global__ void transpose_v_kernel(const bf16* __restrict__ QKV, bf16* __restrict__ Vt) {
  __shared__ short t[64][72];
  const int kt = blockIdx.x, dt = blockIdx.y, b = blockIdx.z;
  const int r = threadIdx.x >> 3;
  const int c8 = (threadIdx.x & 7) * 8;
#pragma unroll
  for (int p = 0; p < 2; ++p) {
    const int row = p * 32 + r;
    const s16x8 v = *(const s16x8*)(QKV + (size_t)(b * S_ + kt * 64 + row) * NQKV_ +
                                    HID_ + D_ + dt * 64 + c8);
    *(s16x8*)&t[row][c8] = v;
  }
  __syncthreads();
#pragma unroll
  for (int p = 0; p < 2; ++p) {
    const int drow = p * 32 + r;
    s16x8 o;
#pragma unroll
    for (int j = 0; j < 8; ++j) o[j] = t[c8 + j][drow];
    *(s16x8*)(Vt + (size_t)(b * D_ + dt * 64 + drow) * S_ + kt * 64 + c8) = o;
  }
}

// ------------- GEMM v5: 128x128, BK=64, dbuf, counted vmcnt, 32x32x16 MFMA -------------
// Same verified 2-phase schedule as v2; MFMA shape swapped to 32x32x16 (2382 vs 2075 TF
// ubench, half the MFMA instruction count). Per wave: 2x2 accumulators of 32x32.
// C/D layout (m74/m101 verified): col = lane&31, row = (r&3)+8*(r>>2)+4*(lane>>5).
template <bool OUT_F32>
__global__ __launch_bounds__(256, 2) void gemm_kernel(const bf16* __restrict__ A,
                                                      const bf16* __restrict__ Bt,
                                                      const float* __restrict__ bias,
                                                      void* __restrict__ Cout,
                                                      int M, int N, int K) {
  __shared__ char lds[65536];
  const int tid = threadIdx.x;
  const int lane = tid & 63;
  const int wave = tid >> 6;
  const int ql = lane & 31;
  const int hi = lane >> 5;

  const int gx = gridDim.x;
  const int lid = blockIdx.y * gx + blockIdx.x;
  const int cpx = (gx * gridDim.y) >> 3;
  const int swz = (lid & 7) * cpx + (lid >> 3);
  const int bn = swz % gx, bm = swz / gx;

  const int rbase = (wave >> 1) * 64;
  const int nbase = (wave & 1) * 64;
  f32x16 acc[2][2] = {};

  int srow[4], scol[4];
#pragma unroll
  for (int o = 0; o < 4; ++o) {
    const int X = o * 4096 + tid * 16;
    const int r = X >> 7, Y = X & 127;
    srow[o] = r;
    scol[o] = Y ^ ((r & 7) << 4);
  }

  const char* Ab = (const char*)A + (size_t)(bm * 128) * K * 2;
  const char* Bb = (const char*)Bt + (size_t)(bn * 128) * K * 2;

#define G_STAGE(buf, kt_)                                                              \
  _Pragma("unroll") for (int o = 0; o < 4; ++o)                                        \
      gload_lds16(Ab + (size_t)srow[o] * (K * 2) + (size_t)(kt_) * 128 + scol[o],      \
                  lds + (buf) + o * 4096 + tid * 16);                                  \
  _Pragma("unroll") for (int o = 0; o < 4; ++o)                                        \
      gload_lds16(Bb + (size_t)srow[o] * (K * 2) + (size_t)(kt_) * 128 + scol[o],      \
                  lds + (buf) + 16384 + o * 4096 + tid * 16);

  G_STAGE(0, 0);

  const int nkt = K >> 6;
  for (int kt = 0; kt < nkt; ++kt) {
    const int cur = (kt & 1) * 32768;
    if (kt < nkt - 1) {
      G_STAGE(cur ^ 32768, kt + 1);
      asm volatile("s_waitcnt vmcnt(8)" ::: "memory");
    } else {
      asm volatile("s_waitcnt vmcnt(0)" ::: "memory");
    }
    __builtin_amdgcn_s_barrier();

    // A/B fragments for 32x32x16: lane ql = row-within-32-tile, hi selects k-half (8 elems)
    bf16x8 af[2][4], bfr[2][4];
#pragma unroll
    for (int mi = 0; mi < 2; ++mi) {
      const int row = rbase + mi * 32 + ql;
#pragma unroll
      for (int ks = 0; ks < 4; ++ks)
        af[mi][ks] =
            *(const bf16x8*)(lds + cur + row * 128 + ((ks * 32 + hi * 16) ^ ((row & 7) << 4)));
    }
#pragma unroll
    for (int ni = 0; ni < 2; ++ni) {
      const int row = nbase + ni * 32 + ql;
#pragma unroll
      for (int ks = 0; ks < 4; ++ks)
        bfr[ni][ks] = *(const bf16x8*)(lds + cur + 16384 + row * 128 +
                                       ((ks * 32 + hi * 16) ^ ((row & 7) << 4)));
    }
#pragma unroll
    for (int ks = 0; ks < 4; ++ks)
#pragma unroll
      for (int mi = 0; mi < 2; ++mi)
#pragma unroll
        for (int ni = 0; ni < 2; ++ni)
          acc[mi][ni] =
              __builtin_amdgcn_mfma_f32_32x32x16_bf16(af[mi][ks], bfr[ni][ks], acc[mi][ni], 0, 0, 0);
    __builtin_amdgcn_s_barrier();
  }
#undef G_STAGE

  // epilogue: row = (r&3)+8*(r>>2)+4*hi within 32-tile, col = ql
#pragma unroll
  for (int ni = 0; ni < 2; ++ni) {
    const int col = bn * 128 + nbase + ni * 32 + ql;
    const float bv = bias[col];
#pragma unroll
    for (int mi = 0; mi < 2; ++mi) {
#pragma unroll
      for (int r = 0; r < 16; ++r) {
        const int row = bm * 128 + rbase + mi * 32 + (r & 3) + 8 * (r >> 2) + 4 * hi;
        const float v = acc[mi][ni][r] + bv;
        if (OUT_F32)
          ((float*)Cout)[(size_t)row * N + col] = v;
        else
          ((bf16*)Cout)[(size_t)row * N + col] = __float2bfloat16(v);
      }
    }
  }
}

// ------------- causal MQA flash attention v11 (unchanged, verified) -------------
__global__ __launch_bounds__(256, 2) void attn_kernel(const bf16* __restrict__ QKV,
                                                      const bf16* __restrict__ Vt,
                                                      bf16* __restrict__ aout) {
  const int pairid = blockIdx.x;  // 0..3
  const int h = blockIdx.y;
  const int b = blockIdx.z;
  const int tid = threadIdx.x;
  const int l = tid & 63;
  const int w = tid >> 6;
  const int ql = l & 31;
  const int hi = l >> 5;

  __shared__ char lds[49152];

  const char* qkv_b = (const char*)QKV + (size_t)b * S_ * (NQKV_ * 2);
  const char* vt_b = (const char*)Vt + (size_t)b * D_ * S_ * 2;

  int kr[4], kc[4], vr[4], vc[4];
#pragma unroll
  for (int o = 0; o < 4; ++o) {
    const int X = w * 4096 + o * 1024 + l * 16;
    const int r = X >> 8;
    kr[o] = r;
    kc[o] = (X & 255) ^ ((r & 15) << 4);
    const int d = X >> 7;
    vr[o] = d;
    vc[o] = (X & 127) ^ ((d & 7) << 4);
  }

#define STAGE_K(kb_off, kt_)                                                          \
  _Pragma("unroll") for (int o = 0; o < 4; ++o)                                       \
      gload_lds16(qkv_b + (size_t)((kt_) * 64 + kr[o]) * (NQKV_ * 2) + HID_ * 2 +     \
                      kc[o],                                                          \
                  lds + (kb_off) + w * 4096 + o * 1024);
#define STAGE_V(kt_)                                                                  \
  _Pragma("unroll") for (int o = 0; o < 4; ++o)                                       \
      gload_lds16(vt_b + (size_t)vr[o] * (S_ * 2) + (kt_) * 128 + vc[o],              \
                  lds + 32768 + w * 4096 + o * 1024);

  for (int pass = 0; pass < 2; ++pass) {
    const int qt = pass == 0 ? (7 - pairid) : pairid;  // long tile first

#pragma unroll
    for (int o = 0; o < 8; ++o) {
      const int X = w * 8192 + o * 1024 + l * 16;
      const int r = X >> 8;
      const int cb = (X & 255) ^ ((r & 15) << 4);
      gload_lds16(qkv_b + (size_t)(qt * 128 + r) * (NQKV_ * 2) + h * 256 + cb, lds + X);
    }
    asm volatile("s_waitcnt vmcnt(0)" ::: "memory");
    __builtin_amdgcn_s_barrier();

    bf16x8 qf[8];
    {
      const int qrow = w * 32 + ql;
#pragma unroll
      for (int ds = 0; ds < 8; ++ds)
        qf[ds] = *(const bf16x8*)(lds + qrow * 256 + ((ds * 32 + hi * 16) ^ ((qrow & 15) << 4)));
    }
    asm volatile("s_waitcnt lgkmcnt(0)" ::: "memory");
    __builtin_amdgcn_sched_barrier(0);
    __builtin_amdgcn_s_barrier();

    STAGE_K(0, 0);

    const float scale = 0.08838834764831845f;
    const int qglob = qt * 128 + w * 32 + ql;
    float mrun = -1e30f, lrun = 0.f;
    f32x16 Oacc[4] = {};

    const int nkt = 2 * qt + 2;
    for (int kt = 0; kt < nkt; ++kt) {
      const int kb = (kt & 1) * 16384;
      STAGE_V(kt);
      if (kt < nkt - 1) {
        STAGE_K(kb ^ 16384, kt + 1);
        asm volatile("s_waitcnt vmcnt(8)" ::: "memory");
      } else {
        asm volatile("s_waitcnt vmcnt(4)" ::: "memory");
      }
      __builtin_amdgcn_s_barrier();
      __builtin_amdgcn_sched_barrier(0);

      const bool skip = (64 * kt >= 128 * qt + 32 * w + 32);
      bf16x8 pa[4];
      if (!skip) {
        const bool need_mask = (64 * kt + 63 > 128 * qt + 32 * w);

        f32x16 s0 = {}, s1 = {};
        __builtin_amdgcn_s_setprio(1);
#pragma unroll
        for (int ds = 0; ds < 8; ++ds) {
          const int krow = ql;
          const bf16x8 kf =
              *(const bf16x8*)(lds + kb + krow * 256 + ((ds * 32 + hi * 16) ^ ((krow & 15) << 4)));
          s0 = __builtin_amdgcn_mfma_f32_32x32x16_bf16(kf, qf[ds], s0, 0, 0, 0);
        }
#pragma unroll
        for (int ds = 0; ds < 8; ++ds) {
          const int krow = 32 + ql;
          const bf16x8 kf =
              *(const bf16x8*)(lds + kb + krow * 256 + ((ds * 32 + hi * 16) ^ ((krow & 15) << 4)));
          s1 = __builtin_amdgcn_mfma_f32_32x32x16_bf16(kf, qf[ds], s1, 0, 0, 0);
        }
        __builtin_amdgcn_s_setprio(0);

#pragma unroll
        for (int r = 0; r < 16; ++r) {
          const int krl = (r & 3) + 8 * (r >> 2) + 4 * hi;
          float v0 = s0[r] * scale, v1 = s1[r] * scale;
          if (need_mask) {
            if (64 * kt + krl > qglob) v0 = -1e30f;
            if (64 * kt + 32 + krl > qglob) v1 = -1e30f;
          }
          s0[r] = v0;
          s1[r] = v1;
        }

        float a0 = -1e30f, a1 = -1e30f, a2 = -1e30f, a3 = -1e30f;
#pragma unroll
        for (int r = 0; r < 16; r += 4) {
          a0 = fmaxf(a0, fmaxf(s0[r], s1[r]));
          a1 = fmaxf(a1, fmaxf(s0[r + 1], s1[r + 1]));
          a2 = fmaxf(a2, fmaxf(s0[r + 2], s1[r + 2]));
          a3 = fmaxf(a3, fmaxf(s0[r + 3], s1[r + 3]));
        }
        float tmax = fmaxf(fmaxf(a0, a1), fmaxf(a2, a3));
        tmax = fmaxf(tmax, __shfl_xor(tmax, 32));

        if (!__all(tmax <= mrun + 8.f)) {
          const float mn = fmaxf(mrun, tmax);
          const float corr = __expf(mrun - mn);
          mrun = mn;
          lrun *= corr;
#pragma unroll
          for (int r = 0; r < 16; ++r) {
            const float cq = __shfl(corr, (r & 3) + 8 * (r >> 2) + 4 * hi);
#pragma unroll
            for (int dt = 0; dt < 4; ++dt) Oacc[dt][r] *= cq;
          }
        }

        float b0 = 0.f, b1 = 0.f, b2 = 0.f, b3 = 0.f;
#pragma unroll
        for (int r = 0; r < 16; r += 4) {
          s0[r] = __expf(s0[r] - mrun);
          s1[r] = __expf(s1[r] - mrun);
          b0 += s0[r] + s1[r];
          s0[r + 1] = __expf(s0[r + 1] - mrun);
          s1[r + 1] = __expf(s1[r + 1] - mrun);
          b1 += s0[r + 1] + s1[r + 1];
          s0[r + 2] = __expf(s0[r + 2] - mrun);
          s1[r + 2] = __expf(s1[r + 2] - mrun);
          b2 += s0[r + 2] + s1[r + 2];
          s0[r + 3] = __expf(s0[r + 3] - mrun);
          s1[r + 3] = __expf(s1[r + 3] - mrun);
          b3 += s0[r + 3] + s1[r + 3];
        }
        float rs = (b0 + b1) + (b2 + b3);
        rs += __shfl_xor(rs, 32);
        lrun += rs;

        unsigned c[16], xc[16];
#pragma unroll
        for (int m = 0; m < 8; ++m) {
          c[m] = pack_bf16(s0[2 * m], s0[2 * m + 1]);
          c[8 + m] = pack_bf16(s1[2 * m], s1[2 * m + 1]);
        }
#pragma unroll
        for (int m = 0; m < 16; ++m) xc[m] = (unsigned)__shfl_xor((int)c[m], 32);

#pragma unroll
        for (int kh = 0; kh < 2; ++kh) {
          const int base = 8 * kh;
          u32x4 f0, f1;
          f0[0] = hi ? xc[base + 2] : c[base + 0];
          f0[1] = hi ? xc[base + 3] : c[base + 1];
          f0[2] = hi ? c[base + 2] : xc[base + 0];
          f0[3] = hi ? c[base + 3] : xc[base + 1];
          f1[0] = hi ? xc[base + 6] : c[base + 4];
          f1[1] = hi ? xc[base + 7] : c[base + 5];
          f1[2] = hi ? c[base + 6] : xc[base + 4];
          f1[3] = hi ? c[base + 7] : xc[base + 5];
          pa[2 * kh] = __builtin_bit_cast(bf16x8, f0);
          pa[2 * kh + 1] = __builtin_bit_cast(bf16x8, f1);
        }
      }

      if (kt < nkt - 1)
        asm volatile("s_waitcnt vmcnt(4)" ::: "memory");
      else
        asm volatile("s_waitcnt vmcnt(0)" ::: "memory");
      __builtin_amdgcn_s_barrier();
      __builtin_amdgcn_sched_barrier(0);

      if (!skip) {
        __builtin_amdgcn_s_setprio(1);
#pragma unroll
        for (int dt = 0; dt < 4; ++dt) {
          const int vrow = dt * 32 + ql;
#pragma unroll
          for (int ks = 0; ks < 4; ++ks) {
            const bf16x8 vf = *(const bf16x8*)(lds + 32768 + vrow * 128 +
                                               ((ks * 32 + hi * 16) ^ ((vrow & 7) << 4)));
            Oacc[dt] = __builtin_amdgcn_mfma_f32_32x32x16_bf16(pa[ks], vf, Oacc[dt], 0, 0, 0);
          }
        }
        __builtin_amdgcn_s_setprio(0);
      }
      __builtin_amdgcn_s_barrier();
    }

#pragma unroll
    for (int r = 0; r < 16; ++r) {
      const int qi = (r & 3) + 8 * (r >> 2) + 4 * hi;
      const float lr = __shfl(lrun, qi);
      const float inv = 1.0f / lr;
      const int token = b * S_ + qt * 128 + w * 32 + qi;
      bf16* orow = aout + (size_t)token * HID_ + h * D_;
#pragma unroll
      for (int dt = 0; dt < 4; ++dt)
        orow[dt * 32 + ql] = __float2bfloat16(Oacc[dt][r] * inv);
    }
    __builtin_amdgcn_s_barrier();
  }
#undef STAGE_K
#undef STAGE_V
}

extern "C" void kernel_launch(void* const* d_in, const int* in_sizes, int n_in,
                              void* d_out, int out_size, void* d_ws, size_t ws_size,
                              hipStream_t stream) {
  const float* hidden = (const float*)d_in[0];
  const float* w_attn = (const float*)d_in[1];
  const float* b_attn = (const float*)d_in[2];
  const float* w_proj = (const float*)d_in[3];
  const float* b_proj = (const float*)d_in[4];

  char* ws = (char*)d_ws;
  char* dob = (char*)d_out;

  bf16* Xbf = (bf16*)ws;
  bf16* WpT = (bf16*)(ws + 33554432);
  bf16* QKV = (bf16*)dob;
  bf16* WaT = (bf16*)(dob + 37748736);
  bf16* Vt = (bf16*)(dob + 50331648);

  cast_bf16_kernel<<<(T_ * HID_) / 8 / 256, 256, 0, stream>>>(hidden, Xbf, (T_ * HID_) / 8);
  transpose_cast_kernel<<<dim3(NQKV_ / 32, HID_ / 32), 256, 0, stream>>>(w_attn, WaT, HID_, NQKV_);
  transpose_cast_kernel<<<dim3(HID_ / 32, HID_ / 32), 256, 0, stream>>>(w_proj, WpT, HID_, HID_);

  gemm_kernel<false><<<dim3(NQKV_ / 128, T_ / 128), 256, 0, stream>>>(
      Xbf, WaT, b_attn, QKV, T_, NQKV_, HID_);

  transpose_v_kernel<<<dim3(S_ / 64, D_ / 64, B_), 256, 0, stream>>>(QKV, Vt);

  attn_kernel<<<dim3(4, H_, B_), 256, 0, stream>>>(QKV, Vt, Xbf);

  gemm_kernel<true><<<dim3(HID_ / 128, T_ / 128), 256, 0, stream>>>(
      Xbf, WpT, b_proj, (float*)d_out, T_, HID_, HID_);
}

// Round 25
// 256.618 us; speedup vs baseline: 1.0727x; 1.0727x over previous
//
#include <hip/hip_runtime.h>
#include <hip/hip_bf16.h>

typedef __hip_bfloat16 bf16;
typedef __attribute__((ext_vector_type(8))) __bf16 bf16x8;
typedef __attribute__((ext_vector_type(4))) float f32x4;
typedef __attribute__((ext_vector_type(16))) float f32x16;
typedef __attribute__((ext_vector_type(8))) short s16x8;
typedef __attribute__((ext_vector_type(4))) unsigned u32x4;

#define B_    8
#define S_    1024
#define H_    16
#define D_    128
#define HID_  2048
#define NQKV_ 2304
#define T_    8192

__device__ __forceinline__ void gload_lds16(const void* g, void* l) {
  __builtin_amdgcn_global_load_lds((const __attribute__((address_space(1))) void*)g,
                                   (__attribute__((address_space(3))) void*)l, 16, 0, 0);
}

__device__ __forceinline__ unsigned pack_bf16(float lo, float hi) {
  return ((unsigned)__bfloat16_as_ushort(__float2bfloat16(hi)) << 16) |
         (unsigned)__bfloat16_as_ushort(__float2bfloat16(lo));
}

// ---------------- cast fp32 -> bf16, 8 elems/thread ----------------
__global__ void cast_bf16_kernel(const float* __restrict__ src, bf16* __restrict__ dst, int n8) {
  const int i = blockIdx.x * 256 + threadIdx.x;
  if (i >= n8) return;
  const float4 a = ((const float4*)src)[2 * i];
  const float4 b = ((const float4*)src)[2 * i + 1];
  s16x8 o;
  o[0] = (short)__bfloat16_as_ushort(__float2bfloat16(a.x));
  o[1] = (short)__bfloat16_as_ushort(__float2bfloat16(a.y));
  o[2] = (short)__bfloat16_as_ushort(__float2bfloat16(a.z));
  o[3] = (short)__bfloat16_as_ushort(__float2bfloat16(a.w));
  o[4] = (short)__bfloat16_as_ushort(__float2bfloat16(b.x));
  o[5] = (short)__bfloat16_as_ushort(__float2bfloat16(b.y));
  o[6] = (short)__bfloat16_as_ushort(__float2bfloat16(b.z));
  o[7] = (short)__bfloat16_as_ushort(__float2bfloat16(b.w));
  ((s16x8*)dst)[i] = o;
}

// ------------- transpose + cast: src (R x C) f32 -> dst (C x R) bf16 -------------
__global__ void transpose_cast_kernel(const float* __restrict__ src, bf16* __restrict__ dst,
                                      int R, int C) {
  __shared__ float tile[32][33];
  const int tx = threadIdx.x & 31, ty = threadIdx.x >> 5;
  const int rt = blockIdx.y * 32, ct = blockIdx.x * 32;
#pragma unroll
  for (int k = 0; k < 4; ++k)
    tile[ty + 8 * k][tx] = src[(size_t)(rt + ty + 8 * k) * C + ct + tx];
  __syncthreads();
#pragma unroll
  for (int k = 0; k < 4; ++k)
    dst[(size_t)(ct + ty + 8 * k) * R + rt + tx] = __float2bfloat16(tile[tx][ty + 8 * k]);
}

// ------------- V transpose: QKV V-cols -> Vt[b][d][k] bf16 -------------
__global__ void transpose_v_kernel(const bf16* __restrict__ QKV, bf16* __restrict__ Vt) {
  __shared__ short t[64][72];
  const int kt = blockIdx.x, dt = blockIdx.y, b = blockIdx.z;
  const int r = threadIdx.x >> 3;
  const int c8 = (threadIdx.x & 7) * 8;
#pragma unroll
  for (int p = 0; p < 2; ++p) {
    const int row = p * 32 + r;
    const s16x8 v = *(const s16x8*)(QKV + (size_t)(b * S_ + kt * 64 + row) * NQKV_ +
                                    HID_ + D_ + dt * 64 + c8);
    *(s16x8*)&t[row][c8] = v;
  }
  __syncthreads();
#pragma unroll
  for (int p = 0; p < 2; ++p) {
    const int drow = p * 32 + r;
    s16x8 o;
#pragma unroll
    for (int j = 0; j < 8; ++j) o[j] = t[c8 + j][drow];
    *(s16x8*)(Vt + (size_t)(b * D_ + dt * 64 + drow) * S_ + kt * 64 + c8) = o;
  }
}

// ------------- GEMM v2 (verified ~1030 TF): 128x128, BK=64, dbuf, counted vmcnt -------------
template <bool OUT_F32>
__global__ __launch_bounds__(256, 2) void gemm_kernel(const bf16* __restrict__ A,
                                                      const bf16* __restrict__ Bt,
                                                      const float* __restrict__ bias,
                                                      void* __restrict__ Cout,
                                                      int M, int N, int K) {
  __shared__ char lds[65536];
  const int tid = threadIdx.x;
  const int lane = tid & 63;
  const int wave = tid >> 6;

  const int gx = gridDim.x;
  const int lid = blockIdx.y * gx + blockIdx.x;
  const int cpx = (gx * gridDim.y) >> 3;
  const int swz = (lid & 7) * cpx + (lid >> 3);
  const int bn = swz % gx, bm = swz / gx;

  const int lrow = lane & 15, lk = lane >> 4;
  const int rbase = (wave >> 1) * 64;
  const int nbase = (wave & 1) * 64;
  f32x4 acc[4][4] = {};

  int srow[4], scol[4];
#pragma unroll
  for (int o = 0; o < 4; ++o) {
    const int X = o * 4096 + tid * 16;
    const int r = X >> 7, Y = X & 127;
    srow[o] = r;
    scol[o] = Y ^ ((r & 7) << 4);
  }

  const char* Ab = (const char*)A + (size_t)(bm * 128) * K * 2;
  const char* Bb = (const char*)Bt + (size_t)(bn * 128) * K * 2;

#define G_STAGE(buf, kt_)                                                              \
  _Pragma("unroll") for (int o = 0; o < 4; ++o)                                        \
      gload_lds16(Ab + (size_t)srow[o] * (K * 2) + (size_t)(kt_) * 128 + scol[o],      \
                  lds + (buf) + o * 4096 + tid * 16);                                  \
  _Pragma("unroll") for (int o = 0; o < 4; ++o)                                        \
      gload_lds16(Bb + (size_t)srow[o] * (K * 2) + (size_t)(kt_) * 128 + scol[o],      \
                  lds + (buf) + 16384 + o * 4096 + tid * 16);

  G_STAGE(0, 0);

  const int nkt = K >> 6;
  for (int kt = 0; kt < nkt; ++kt) {
    const int cur = (kt & 1) * 32768;
    if (kt < nkt - 1) {
      G_STAGE(cur ^ 32768, kt + 1);
      asm volatile("s_waitcnt vmcnt(8)" ::: "memory");
    } else {
      asm volatile("s_waitcnt vmcnt(0)" ::: "memory");
    }
    __builtin_amdgcn_s_barrier();

    bf16x8 af[4][2], bfr[4][2];
#pragma unroll
    for (int mi = 0; mi < 4; ++mi) {
      const int row = rbase + mi * 16 + lrow;
#pragma unroll
      for (int kk = 0; kk < 2; ++kk)
        af[mi][kk] =
            *(const bf16x8*)(lds + cur + row * 128 + ((kk * 64 + lk * 16) ^ ((row & 7) << 4)));
    }
#pragma unroll
    for (int ni = 0; ni < 4; ++ni) {
      const int row = nbase + ni * 16 + lrow;
#pragma unroll
      for (int kk = 0; kk < 2; ++kk)
        bfr[ni][kk] = *(const bf16x8*)(lds + cur + 16384 + row * 128 +
                                       ((kk * 64 + lk * 16) ^ ((row & 7) << 4)));
    }
#pragma unroll
    for (int kk = 0; kk < 2; ++kk)
#pragma unroll
      for (int mi = 0; mi < 4; ++mi)
#pragma unroll
        for (int ni = 0; ni < 4; ++ni)
          acc[mi][ni] =
              __builtin_amdgcn_mfma_f32_16x16x32_bf16(af[mi][kk], bfr[ni][kk], acc[mi][ni], 0, 0, 0);
    __builtin_amdgcn_s_barrier();
  }
#undef G_STAGE

#pragma unroll
  for (int ni = 0; ni < 4; ++ni) {
    const int col = bn * 128 + nbase + ni * 16 + lrow;
    const float bv = bias[col];
#pragma unroll
    for (int mi = 0; mi < 4; ++mi) {
      const int row0 = bm * 128 + rbase + mi * 16 + lk * 4;
#pragma unroll
      for (int r = 0; r < 4; ++r) {
        const float v = acc[mi][ni][r] + bv;
        if (OUT_F32)
          ((float*)Cout)[(size_t)(row0 + r) * N + col] = v;
        else
          ((bf16*)Cout)[(size_t)(row0 + r) * N + col] = __float2bfloat16(v);
      }
    }
  }
}

// ------------- causal MQA flash attention v11: 4-wave blocks, 128-row paired q-tiles -------------
// grid (4 pairs, H, B), 256 threads = 4 waves x 32 q-rows. Pair p = tiles {7-p, p} (128 rows
// each) -> every block exactly 18 k-iterations (balanced), 512 blocks = 2/CU co-resident.
// LDS 48KB: K dbuf @0/16K (64x256B swz), V single @32K (128x128B swz). Inner code = v7.
__global__ __launch_bounds__(256, 2) void attn_kernel(const bf16* __restrict__ QKV,
                                                      const bf16* __restrict__ Vt,
                                                      bf16* __restrict__ aout) {
  const int pairid = blockIdx.x;  // 0..3
  const int h = blockIdx.y;
  const int b = blockIdx.z;
  const int tid = threadIdx.x;
  const int l = tid & 63;
  const int w = tid >> 6;
  const int ql = l & 31;
  const int hi = l >> 5;

  __shared__ char lds[49152];

  const char* qkv_b = (const char*)QKV + (size_t)b * S_ * (NQKV_ * 2);
  const char* vt_b = (const char*)Vt + (size_t)b * D_ * S_ * 2;

  int kr[4], kc[4], vr[4], vc[4];
#pragma unroll
  for (int o = 0; o < 4; ++o) {
    const int X = w * 4096 + o * 1024 + l * 16;
    const int r = X >> 8;
    kr[o] = r;
    kc[o] = (X & 255) ^ ((r & 15) << 4);
    const int d = X >> 7;
    vr[o] = d;
    vc[o] = (X & 127) ^ ((d & 7) << 4);
  }

#define STAGE_K(kb_off, kt_)                                                          \
  _Pragma("unroll") for (int o = 0; o < 4; ++o)                                       \
      gload_lds16(qkv_b + (size_t)((kt_) * 64 + kr[o]) * (NQKV_ * 2) + HID_ * 2 +     \
                      kc[o],                                                          \
                  lds + (kb_off) + w * 4096 + o * 1024);
#define STAGE_V(kt_)                                                                  \
  _Pragma("unroll") for (int o = 0; o < 4; ++o)                                       \
      gload_lds16(vt_b + (size_t)vr[o] * (S_ * 2) + (kt_) * 128 + vc[o],              \
                  lds + 32768 + w * 4096 + o * 1024);

  for (int pass = 0; pass < 2; ++pass) {
    const int qt = pass == 0 ? (7 - pairid) : pairid;  // long tile first

    // ---- stage Q (128 rows x 256B = 32KB) into K-dbuf area, read frags ----
#pragma unroll
    for (int o = 0; o < 8; ++o) {
      const int X = w * 8192 + o * 1024 + l * 16;
      const int r = X >> 8;
      const int cb = (X & 255) ^ ((r & 15) << 4);
      gload_lds16(qkv_b + (size_t)(qt * 128 + r) * (NQKV_ * 2) + h * 256 + cb, lds + X);
    }
    asm volatile("s_waitcnt vmcnt(0)" ::: "memory");
    __builtin_amdgcn_s_barrier();

    bf16x8 qf[8];
    {
      const int qrow = w * 32 + ql;
#pragma unroll
      for (int ds = 0; ds < 8; ++ds)
        qf[ds] = *(const bf16x8*)(lds + qrow * 256 + ((ds * 32 + hi * 16) ^ ((qrow & 15) << 4)));
    }
    asm volatile("s_waitcnt lgkmcnt(0)" ::: "memory");
    __builtin_amdgcn_sched_barrier(0);
    __builtin_amdgcn_s_barrier();  // all waves done reading Q before tile-0 staging

    STAGE_K(0, 0);

    const float scale = 0.08838834764831845f;
    const int qglob = qt * 128 + w * 32 + ql;
    float mrun = -1e30f, lrun = 0.f;
    f32x16 Oacc[4] = {};

    const int nkt = 2 * qt + 2;
    for (int kt = 0; kt < nkt; ++kt) {
      const int kb = (kt & 1) * 16384;
      STAGE_V(kt);
      if (kt < nkt - 1) {
        STAGE_K(kb ^ 16384, kt + 1);
        asm volatile("s_waitcnt vmcnt(8)" ::: "memory");
      } else {
        asm volatile("s_waitcnt vmcnt(4)" ::: "memory");
      }
      __builtin_amdgcn_s_barrier();
      __builtin_amdgcn_sched_barrier(0);

      const bool skip = (64 * kt >= 128 * qt + 32 * w + 32);
      bf16x8 pa[4];
      if (!skip) {
        const bool need_mask = (64 * kt + 63 > 128 * qt + 32 * w);

        f32x16 s0 = {}, s1 = {};
        __builtin_amdgcn_s_setprio(1);
#pragma unroll
        for (int ds = 0; ds < 8; ++ds) {
          const int krow = ql;
          const bf16x8 kf =
              *(const bf16x8*)(lds + kb + krow * 256 + ((ds * 32 + hi * 16) ^ ((krow & 15) << 4)));
          s0 = __builtin_amdgcn_mfma_f32_32x32x16_bf16(kf, qf[ds], s0, 0, 0, 0);
        }
#pragma unroll
        for (int ds = 0; ds < 8; ++ds) {
          const int krow = 32 + ql;
          const bf16x8 kf =
              *(const bf16x8*)(lds + kb + krow * 256 + ((ds * 32 + hi * 16) ^ ((krow & 15) << 4)));
          s1 = __builtin_amdgcn_mfma_f32_32x32x16_bf16(kf, qf[ds], s1, 0, 0, 0);
        }
        __builtin_amdgcn_s_setprio(0);

#pragma unroll
        for (int r = 0; r < 16; ++r) {
          const int krl = (r & 3) + 8 * (r >> 2) + 4 * hi;
          float v0 = s0[r] * scale, v1 = s1[r] * scale;
          if (need_mask) {
            if (64 * kt + krl > qglob) v0 = -1e30f;
            if (64 * kt + 32 + krl > qglob) v1 = -1e30f;
          }
          s0[r] = v0;
          s1[r] = v1;
        }

        float a0 = -1e30f, a1 = -1e30f, a2 = -1e30f, a3 = -1e30f;
#pragma unroll
        for (int r = 0; r < 16; r += 4) {
          a0 = fmaxf(a0, fmaxf(s0[r], s1[r]));
          a1 = fmaxf(a1, fmaxf(s0[r + 1], s1[r + 1]));
          a2 = fmaxf(a2, fmaxf(s0[r + 2], s1[r + 2]));
          a3 = fmaxf(a3, fmaxf(s0[r + 3], s1[r + 3]));
        }
        float tmax = fmaxf(fmaxf(a0, a1), fmaxf(a2, a3));
        tmax = fmaxf(tmax, __shfl_xor(tmax, 32));

        if (!__all(tmax <= mrun + 8.f)) {
          const float mn = fmaxf(mrun, tmax);
          const float corr = __expf(mrun - mn);
          mrun = mn;
          lrun *= corr;
#pragma unroll
          for (int r = 0; r < 16; ++r) {
            const float cq = __shfl(corr, (r & 3) + 8 * (r >> 2) + 4 * hi);
#pragma unroll
            for (int dt = 0; dt < 4; ++dt) Oacc[dt][r] *= cq;
          }
        }

        float b0 = 0.f, b1 = 0.f, b2 = 0.f, b3 = 0.f;
#pragma unroll
        for (int r = 0; r < 16; r += 4) {
          s0[r] = __expf(s0[r] - mrun);
          s1[r] = __expf(s1[r] - mrun);
          b0 += s0[r] + s1[r];
          s0[r + 1] = __expf(s0[r + 1] - mrun);
          s1[r + 1] = __expf(s1[r + 1] - mrun);
          b1 += s0[r + 1] + s1[r + 1];
          s0[r + 2] = __expf(s0[r + 2] - mrun);
          s1[r + 2] = __expf(s1[r + 2] - mrun);
          b2 += s0[r + 2] + s1[r + 2];
          s0[r + 3] = __expf(s0[r + 3] - mrun);
          s1[r + 3] = __expf(s1[r + 3] - mrun);
          b3 += s0[r + 3] + s1[r + 3];
        }
        float rs = (b0 + b1) + (b2 + b3);
        rs += __shfl_xor(rs, 32);
        lrun += rs;

        unsigned c[16], xc[16];
#pragma unroll
        for (int m = 0; m < 8; ++m) {
          c[m] = pack_bf16(s0[2 * m], s0[2 * m + 1]);
          c[8 + m] = pack_bf16(s1[2 * m], s1[2 * m + 1]);
        }
#pragma unroll
        for (int m = 0; m < 16; ++m) xc[m] = (unsigned)__shfl_xor((int)c[m], 32);

#pragma unroll
        for (int kh = 0; kh < 2; ++kh) {
          const int base = 8 * kh;
          u32x4 f0, f1;
          f0[0] = hi ? xc[base + 2] : c[base + 0];
          f0[1] = hi ? xc[base + 3] : c[base + 1];
          f0[2] = hi ? c[base + 2] : xc[base + 0];
          f0[3] = hi ? c[base + 3] : xc[base + 1];
          f1[0] = hi ? xc[base + 6] : c[base + 4];
          f1[1] = hi ? xc[base + 7] : c[base + 5];
          f1[2] = hi ? c[base + 6] : xc[base + 4];
          f1[3] = hi ? c[base + 7] : xc[base + 5];
          pa[2 * kh] = __builtin_bit_cast(bf16x8, f0);
          pa[2 * kh + 1] = __builtin_bit_cast(bf16x8, f1);
        }
      }

      if (kt < nkt - 1)
        asm volatile("s_waitcnt vmcnt(4)" ::: "memory");
      else
        asm volatile("s_waitcnt vmcnt(0)" ::: "memory");
      __builtin_amdgcn_s_barrier();
      __builtin_amdgcn_sched_barrier(0);

      if (!skip) {
        __builtin_amdgcn_s_setprio(1);
#pragma unroll
        for (int dt = 0; dt < 4; ++dt) {
          const int vrow = dt * 32 + ql;
#pragma unroll
          for (int ks = 0; ks < 4; ++ks) {
            const bf16x8 vf = *(const bf16x8*)(lds + 32768 + vrow * 128 +
                                               ((ks * 32 + hi * 16) ^ ((vrow & 7) << 4)));
            Oacc[dt] = __builtin_amdgcn_mfma_f32_32x32x16_bf16(pa[ks], vf, Oacc[dt], 0, 0, 0);
          }
        }
        __builtin_amdgcn_s_setprio(0);
      }
      __builtin_amdgcn_s_barrier();
    }

    // ---- epilogue for this q-tile ----
#pragma unroll
    for (int r = 0; r < 16; ++r) {
      const int qi = (r & 3) + 8 * (r >> 2) + 4 * hi;
      const float lr = __shfl(lrun, qi);
      const float inv = 1.0f / lr;
      const int token = b * S_ + qt * 128 + w * 32 + qi;
      bf16* orow = aout + (size_t)token * HID_ + h * D_;
#pragma unroll
      for (int dt = 0; dt < 4; ++dt)
        orow[dt * 32 + ql] = __float2bfloat16(Oacc[dt][r] * inv);
    }
    __builtin_amdgcn_s_barrier();  // all waves done before next pass restages Q
  }
#undef STAGE_K
#undef STAGE_V
}

extern "C" void kernel_launch(void* const* d_in, const int* in_sizes, int n_in,
                              void* d_out, int out_size, void* d_ws, size_t ws_size,
                              hipStream_t stream) {
  const float* hidden = (const float*)d_in[0];
  const float* w_attn = (const float*)d_in[1];
  const float* b_attn = (const float*)d_in[2];
  const float* w_proj = (const float*)d_in[3];
  const float* b_proj = (const float*)d_in[4];

  char* ws = (char*)d_ws;
  char* dob = (char*)d_out;

  bf16* Xbf = (bf16*)ws;
  bf16* WpT = (bf16*)(ws + 33554432);
  bf16* QKV = (bf16*)dob;
  bf16* WaT = (bf16*)(dob + 37748736);
  bf16* Vt = (bf16*)(dob + 50331648);

  cast_bf16_kernel<<<(T_ * HID_) / 8 / 256, 256, 0, stream>>>(hidden, Xbf, (T_ * HID_) / 8);
  transpose_cast_kernel<<<dim3(NQKV_ / 32, HID_ / 32), 256, 0, stream>>>(w_attn, WaT, HID_, NQKV_);
  transpose_cast_kernel<<<dim3(HID_ / 32, HID_ / 32), 256, 0, stream>>>(w_proj, WpT, HID_, HID_);

  gemm_kernel<false><<<dim3(NQKV_ / 128, T_ / 128), 256, 0, stream>>>(
      Xbf, WaT, b_attn, QKV, T_, NQKV_, HID_);

  transpose_v_kernel<<<dim3(S_ / 64, D_ / 64, B_), 256, 0, stream>>>(QKV, Vt);

  attn_kernel<<<dim3(4, H_, B_), 256, 0, stream>>>(QKV, Vt, Xbf);

  gemm_kernel<true><<<dim3(HID_ / 128, T_ / 128), 256, 0, stream>>>(
      Xbf, WpT, b_proj, (float*)d_out, T_, HID_, HID_);
}

// Round 26
// 256.277 us; speedup vs baseline: 1.0742x; 1.0013x over previous
//
#include <hip/hip_runtime.h>
#include <hip/hip_bf16.h>

typedef __hip_bfloat16 bf16;
typedef __attribute__((ext_vector_type(8))) __bf16 bf16x8;
typedef __attribute__((ext_vector_type(4))) float f32x4;
typedef __attribute__((ext_vector_type(16))) float f32x16;
typedef __attribute__((ext_vector_type(8))) short s16x8;
typedef __attribute__((ext_vector_type(4))) unsigned u32x4;

#define B_    8
#define S_    1024
#define H_    16
#define D_    128
#define HID_  2048
#define NQKV_ 2304
#define T_    8192

__device__ __forceinline__ void gload_lds16(const void* g, void* l) {
  __builtin_amdgcn_global_load_lds((const __attribute__((address_space(1))) void*)g,
                                   (__attribute__((address_space(3))) void*)l, 16, 0, 0);
}

__device__ __forceinline__ unsigned pack_bf16(float lo, float hi) {
  return ((unsigned)__bfloat16_as_ushort(__float2bfloat16(hi)) << 16) |
         (unsigned)__bfloat16_as_ushort(__float2bfloat16(lo));
}

// ---------------- cast fp32 -> bf16, 8 elems/thread ----------------
__global__ void cast_bf16_kernel(const float* __restrict__ src, bf16* __restrict__ dst, int n8) {
  const int i = blockIdx.x * 256 + threadIdx.x;
  if (i >= n8) return;
  const float4 a = ((const float4*)src)[2 * i];
  const float4 b = ((const float4*)src)[2 * i + 1];
  s16x8 o;
  o[0] = (short)__bfloat16_as_ushort(__float2bfloat16(a.x));
  o[1] = (short)__bfloat16_as_ushort(__float2bfloat16(a.y));
  o[2] = (short)__bfloat16_as_ushort(__float2bfloat16(a.z));
  o[3] = (short)__bfloat16_as_ushort(__float2bfloat16(a.w));
  o[4] = (short)__bfloat16_as_ushort(__float2bfloat16(b.x));
  o[5] = (short)__bfloat16_as_ushort(__float2bfloat16(b.y));
  o[6] = (short)__bfloat16_as_ushort(__float2bfloat16(b.z));
  o[7] = (short)__bfloat16_as_ushort(__float2bfloat16(b.w));
  ((s16x8*)dst)[i] = o;
}

// ------------- transpose + cast: src (R x C) f32 -> dst (C x R) bf16 -------------
__global__ void transpose_cast_kernel(const float* __restrict__ src, bf16* __restrict__ dst,
                                      int R, int C) {
  __shared__ float tile[32][33];
  const int tx = threadIdx.x & 31, ty = threadIdx.x >> 5;
  const int rt = blockIdx.y * 32, ct = blockIdx.x * 32;
#pragma unroll
  for (int k = 0; k < 4; ++k)
    tile[ty + 8 * k][tx] = src[(size_t)(rt + ty + 8 * k) * C + ct + tx];
  __syncthreads();
#pragma unroll
  for (int k = 0; k < 4; ++k)
    dst[(size_t)(ct + ty + 8 * k) * R + rt + tx] = __float2bfloat16(tile[tx][ty + 8 * k]);
}

// ------------- V transpose: QKV V-cols -> Vt[b][d][k] bf16 -------------
__global__ void transpose_v_kernel(const bf16* __restrict__ QKV, bf16* __restrict__ Vt) {
  __shared__ short t[64][72];
  const int kt = blockIdx.x, dt = blockIdx.y, b = blockIdx.z;
  const int r = threadIdx.x >> 3;
  const int c8 = (threadIdx.x & 7) * 8;
#pragma unroll
  for (int p = 0; p < 2; ++p) {
    const int row = p * 32 + r;
    const s16x8 v = *(const s16x8*)(QKV + (size_t)(b * S_ + kt * 64 + row) * NQKV_ +
                                    HID_ + D_ + dt * 64 + c8);
    *(s16x8*)&t[row][c8] = v;
  }
  __syncthreads();
#pragma unroll
  for (int p = 0; p < 2; ++p) {
    const int drow = p * 32 + r;
    s16x8 o;
#pragma unroll
    for (int j = 0; j < 8; ++j) o[j] = t[c8 + j][drow];
    *(s16x8*)(Vt + (size_t)(b * D_ + dt * 64 + drow) * S_ + kt * 64 + c8) = o;
  }
}

// ------------- GEMM v2 (verified ~1030 TF): 128x128, BK=64, dbuf, counted vmcnt -------------
template <bool OUT_F32>
__global__ __launch_bounds__(256, 2) void gemm_kernel(const bf16* __restrict__ A,
                                                      const bf16* __restrict__ Bt,
                                                      const float* __restrict__ bias,
                                                      void* __restrict__ Cout,
                                                      int M, int N, int K) {
  __shared__ char lds[65536];
  const int tid = threadIdx.x;
  const int lane = tid & 63;
  const int wave = tid >> 6;

  const int gx = gridDim.x;
  const int lid = blockIdx.y * gx + blockIdx.x;
  const int cpx = (gx * gridDim.y) >> 3;
  const int swz = (lid & 7) * cpx + (lid >> 3);
  const int bn = swz % gx, bm = swz / gx;

  const int lrow = lane & 15, lk = lane >> 4;
  const int rbase = (wave >> 1) * 64;
  const int nbase = (wave & 1) * 64;
  f32x4 acc[4][4] = {};

  int srow[4], scol[4];
#pragma unroll
  for (int o = 0; o < 4; ++o) {
    const int X = o * 4096 + tid * 16;
    const int r = X >> 7, Y = X & 127;
    srow[o] = r;
    scol[o] = Y ^ ((r & 7) << 4);
  }

  const char* Ab = (const char*)A + (size_t)(bm * 128) * K * 2;
  const char* Bb = (const char*)Bt + (size_t)(bn * 128) * K * 2;

#define G_STAGE(buf, kt_)                                                              \
  _Pragma("unroll") for (int o = 0; o < 4; ++o)                                        \
      gload_lds16(Ab + (size_t)srow[o] * (K * 2) + (size_t)(kt_) * 128 + scol[o],      \
                  lds + (buf) + o * 4096 + tid * 16);                                  \
  _Pragma("unroll") for (int o = 0; o < 4; ++o)                                        \
      gload_lds16(Bb + (size_t)srow[o] * (K * 2) + (size_t)(kt_) * 128 + scol[o],      \
                  lds + (buf) + 16384 + o * 4096 + tid * 16);

  G_STAGE(0, 0);

  const int nkt = K >> 6;
  for (int kt = 0; kt < nkt; ++kt) {
    const int cur = (kt & 1) * 32768;
    if (kt < nkt - 1) {
      G_STAGE(cur ^ 32768, kt + 1);
      asm volatile("s_waitcnt vmcnt(8)" ::: "memory");
    } else {
      asm volatile("s_waitcnt vmcnt(0)" ::: "memory");
    }
    __builtin_amdgcn_s_barrier();

    bf16x8 af[4][2], bfr[4][2];
#pragma unroll
    for (int mi = 0; mi < 4; ++mi) {
      const int row = rbase + mi * 16 + lrow;
#pragma unroll
      for (int kk = 0; kk < 2; ++kk)
        af[mi][kk] =
            *(const bf16x8*)(lds + cur + row * 128 + ((kk * 64 + lk * 16) ^ ((row & 7) << 4)));
    }
#pragma unroll
    for (int ni = 0; ni < 4; ++ni) {
      const int row = nbase + ni * 16 + lrow;
#pragma unroll
      for (int kk = 0; kk < 2; ++kk)
        bfr[ni][kk] = *(const bf16x8*)(lds + cur + 16384 + row * 128 +
                                       ((kk * 64 + lk * 16) ^ ((row & 7) << 4)));
    }
#pragma unroll
    for (int kk = 0; kk < 2; ++kk)
#pragma unroll
      for (int mi = 0; mi < 4; ++mi)
#pragma unroll
        for (int ni = 0; ni < 4; ++ni)
          acc[mi][ni] =
              __builtin_amdgcn_mfma_f32_16x16x32_bf16(af[mi][kk], bfr[ni][kk], acc[mi][ni], 0, 0, 0);
    __builtin_amdgcn_s_barrier();
  }
#undef G_STAGE

#pragma unroll
  for (int ni = 0; ni < 4; ++ni) {
    const int col = bn * 128 + nbase + ni * 16 + lrow;
    const float bv = bias[col];
#pragma unroll
    for (int mi = 0; mi < 4; ++mi) {
      const int row0 = bm * 128 + rbase + mi * 16 + lk * 4;
#pragma unroll
      for (int r = 0; r < 4; ++r) {
        const float v = acc[mi][ni][r] + bv;
        if (OUT_F32)
          ((float*)Cout)[(size_t)(row0 + r) * N + col] = v;
        else
          ((bf16*)Cout)[(size_t)(row0 + r) * N + col] = __float2bfloat16(v);
      }
    }
  }
}

// ------------- causal MQA flash attention v11: 4-wave blocks, 128-row paired q-tiles -------------
__global__ __launch_bounds__(256, 2) void attn_kernel(const bf16* __restrict__ QKV,
                                                      const bf16* __restrict__ Vt,
                                                      bf16* __restrict__ aout) {
  const int pairid = blockIdx.x;  // 0..3
  const int h = blockIdx.y;
  const int b = blockIdx.z;
  const int tid = threadIdx.x;
  const int l = tid & 63;
  const int w = tid >> 6;
  const int ql = l & 31;
  const int hi = l >> 5;

  __shared__ char lds[49152];

  const char* qkv_b = (const char*)QKV + (size_t)b * S_ * (NQKV_ * 2);
  const char* vt_b = (const char*)Vt + (size_t)b * D_ * S_ * 2;

  int kr[4], kc[4], vr[4], vc[4];
#pragma unroll
  for (int o = 0; o < 4; ++o) {
    const int X = w * 4096 + o * 1024 + l * 16;
    const int r = X >> 8;
    kr[o] = r;
    kc[o] = (X & 255) ^ ((r & 15) << 4);
    const int d = X >> 7;
    vr[o] = d;
    vc[o] = (X & 127) ^ ((d & 7) << 4);
  }

#define STAGE_K(kb_off, kt_)                                                          \
  _Pragma("unroll") for (int o = 0; o < 4; ++o)                                       \
      gload_lds16(qkv_b + (size_t)((kt_) * 64 + kr[o]) * (NQKV_ * 2) + HID_ * 2 +     \
                      kc[o],                                                          \
                  lds + (kb_off) + w * 4096 + o * 1024);
#define STAGE_V(kt_)                                                                  \
  _Pragma("unroll") for (int o = 0; o < 4; ++o)                                       \
      gload_lds16(vt_b + (size_t)vr[o] * (S_ * 2) + (kt_) * 128 + vc[o],              \
                  lds + 32768 + w * 4096 + o * 1024);

  for (int pass = 0; pass < 2; ++pass) {
    const int qt = pass == 0 ? (7 - pairid) : pairid;  // long tile first

    // ---- stage Q (128 rows x 256B = 32KB) into K-dbuf area, read frags ----
#pragma unroll
    for (int o = 0; o < 8; ++o) {
      const int X = w * 8192 + o * 1024 + l * 16;
      const int r = X >> 8;
      const int cb = (X & 255) ^ ((r & 15) << 4);
      gload_lds16(qkv_b + (size_t)(qt * 128 + r) * (NQKV_ * 2) + h * 256 + cb, lds + X);
    }
    asm volatile("s_waitcnt vmcnt(0)" ::: "memory");
    __builtin_amdgcn_s_barrier();

    bf16x8 qf[8];
    {
      const int qrow = w * 32 + ql;
#pragma unroll
      for (int ds = 0; ds < 8; ++ds)
        qf[ds] = *(const bf16x8*)(lds + qrow * 256 + ((ds * 32 + hi * 16) ^ ((qrow & 15) << 4)));
    }
    asm volatile("s_waitcnt lgkmcnt(0)" ::: "memory");
    __builtin_amdgcn_sched_barrier(0);
    __builtin_amdgcn_s_barrier();  // all waves done reading Q before tile-0 staging

    STAGE_K(0, 0);

    const float scale = 0.08838834764831845f;
    const int qglob = qt * 128 + w * 32 + ql;
    float mrun = -1e30f, lrun = 0.f;
    f32x16 Oacc[4] = {};

    const int nkt = 2 * qt + 2;
    for (int kt = 0; kt < nkt; ++kt) {
      const int kb = (kt & 1) * 16384;
      STAGE_V(kt);
      if (kt < nkt - 1) {
        STAGE_K(kb ^ 16384, kt + 1);
        asm volatile("s_waitcnt vmcnt(8)" ::: "memory");
      } else {
        asm volatile("s_waitcnt vmcnt(4)" ::: "memory");
      }
      __builtin_amdgcn_s_barrier();
      __builtin_amdgcn_sched_barrier(0);

      const bool skip = (64 * kt >= 128 * qt + 32 * w + 32);
      bf16x8 pa[4];
      if (!skip) {
        const bool need_mask = (64 * kt + 63 > 128 * qt + 32 * w);

        f32x16 s0 = {}, s1 = {};
        __builtin_amdgcn_s_setprio(1);
#pragma unroll
        for (int ds = 0; ds < 8; ++ds) {
          const int krow = ql;
          const bf16x8 kf =
              *(const bf16x8*)(lds + kb + krow * 256 + ((ds * 32 + hi * 16) ^ ((krow & 15) << 4)));
          s0 = __builtin_amdgcn_mfma_f32_32x32x16_bf16(kf, qf[ds], s0, 0, 0, 0);
        }
#pragma unroll
        for (int ds = 0; ds < 8; ++ds) {
          const int krow = 32 + ql;
          const bf16x8 kf =
              *(const bf16x8*)(lds + kb + krow * 256 + ((ds * 32 + hi * 16) ^ ((krow & 15) << 4)));
          s1 = __builtin_amdgcn_mfma_f32_32x32x16_bf16(kf, qf[ds], s1, 0, 0, 0);
        }
        __builtin_amdgcn_s_setprio(0);

#pragma unroll
        for (int r = 0; r < 16; ++r) {
          const int krl = (r & 3) + 8 * (r >> 2) + 4 * hi;
          float v0 = s0[r] * scale, v1 = s1[r] * scale;
          if (need_mask) {
            if (64 * kt + krl > qglob) v0 = -1e30f;
            if (64 * kt + 32 + krl > qglob) v1 = -1e30f;
          }
          s0[r] = v0;
          s1[r] = v1;
        }

        float a0 = -1e30f, a1 = -1e30f, a2 = -1e30f, a3 = -1e30f;
#pragma unroll
        for (int r = 0; r < 16; r += 4) {
          a0 = fmaxf(a0, fmaxf(s0[r], s1[r]));
          a1 = fmaxf(a1, fmaxf(s0[r + 1], s1[r + 1]));
          a2 = fmaxf(a2, fmaxf(s0[r + 2], s1[r + 2]));
          a3 = fmaxf(a3, fmaxf(s0[r + 3], s1[r + 3]));
        }
        float tmax = fmaxf(fmaxf(a0, a1), fmaxf(a2, a3));
        tmax = fmaxf(tmax, __shfl_xor(tmax, 32));

        if (!__all(tmax <= mrun + 8.f)) {
          const float mn = fmaxf(mrun, tmax);
          const float corr = __expf(mrun - mn);
          mrun = mn;
          lrun *= corr;
#pragma unroll
          for (int r = 0; r < 16; ++r) {
            const float cq = __shfl(corr, (r & 3) + 8 * (r >> 2) + 4 * hi);
#pragma unroll
            for (int dt = 0; dt < 4; ++dt) Oacc[dt][r] *= cq;
          }
        }

        float b0 = 0.f, b1 = 0.f, b2 = 0.f, b3 = 0.f;
#pragma unroll
        for (int r = 0; r < 16; r += 4) {
          s0[r] = __expf(s0[r] - mrun);
          s1[r] = __expf(s1[r] - mrun);
          b0 += s0[r] + s1[r];
          s0[r + 1] = __expf(s0[r + 1] - mrun);
          s1[r + 1] = __expf(s1[r + 1] - mrun);
          b1 += s0[r + 1] + s1[r + 1];
          s0[r + 2] = __expf(s0[r + 2] - mrun);
          s1[r + 2] = __expf(s1[r + 2] - mrun);
          b2 += s0[r + 2] + s1[r + 2];
          s0[r + 3] = __expf(s0[r + 3] - mrun);
          s1[r + 3] = __expf(s1[r + 3] - mrun);
          b3 += s0[r + 3] + s1[r + 3];
        }
        float rs = (b0 + b1) + (b2 + b3);
        rs += __shfl_xor(rs, 32);
        lrun += rs;

        unsigned c[16], xc[16];
#pragma unroll
        for (int m = 0; m < 8; ++m) {
          c[m] = pack_bf16(s0[2 * m], s0[2 * m + 1]);
          c[8 + m] = pack_bf16(s1[2 * m], s1[2 * m + 1]);
        }
#pragma unroll
        for (int m = 0; m < 16; ++m) xc[m] = (unsigned)__shfl_xor((int)c[m], 32);

#pragma unroll
        for (int kh = 0; kh < 2; ++kh) {
          const int base = 8 * kh;
          u32x4 f0, f1;
          f0[0] = hi ? xc[base + 2] : c[base + 0];
          f0[1] = hi ? xc[base + 3] : c[base + 1];
          f0[2] = hi ? c[base + 2] : xc[base + 0];
          f0[3] = hi ? c[base + 3] : xc[base + 1];
          f1[0] = hi ? xc[base + 6] : c[base + 4];
          f1[1] = hi ? xc[base + 7] : c[base + 5];
          f1[2] = hi ? c[base + 6] : xc[base + 4];
          f1[3] = hi ? c[base + 7] : xc[base + 5];
          pa[2 * kh] = __builtin_bit_cast(bf16x8, f0);
          pa[2 * kh + 1] = __builtin_bit_cast(bf16x8, f1);
        }
      }

      if (kt < nkt - 1)
        asm volatile("s_waitcnt vmcnt(4)" ::: "memory");
      else
        asm volatile("s_waitcnt vmcnt(0)" ::: "memory");
      __builtin_amdgcn_s_barrier();
      __builtin_amdgcn_sched_barrier(0);

      if (!skip) {
        __builtin_amdgcn_s_setprio(1);
#pragma unroll
        for (int dt = 0; dt < 4; ++dt) {
          const int vrow = dt * 32 + ql;
#pragma unroll
          for (int ks = 0; ks < 4; ++ks) {
            const bf16x8 vf = *(const bf16x8*)(lds + 32768 + vrow * 128 +
                                               ((ks * 32 + hi * 16) ^ ((vrow & 7) << 4)));
            Oacc[dt] = __builtin_amdgcn_mfma_f32_32x32x16_bf16(pa[ks], vf, Oacc[dt], 0, 0, 0);
          }
        }
        __builtin_amdgcn_s_setprio(0);
      }
      __builtin_amdgcn_s_barrier();
    }

    // ---- epilogue for this q-tile ----
#pragma unroll
    for (int r = 0; r < 16; ++r) {
      const int qi = (r & 3) + 8 * (r >> 2) + 4 * hi;
      const float lr = __shfl(lrun, qi);
      const float inv = 1.0f / lr;
      const int token = b * S_ + qt * 128 + w * 32 + qi;
      bf16* orow = aout + (size_t)token * HID_ + h * D_;
#pragma unroll
      for (int dt = 0; dt < 4; ++dt)
        orow[dt * 32 + ql] = __float2bfloat16(Oacc[dt][r] * inv);
    }
    __builtin_amdgcn_s_barrier();  // all waves done before next pass restages Q
  }
#undef STAGE_K
#undef STAGE_V
}

extern "C" void kernel_launch(void* const* d_in, const int* in_sizes, int n_in,
                              void* d_out, int out_size, void* d_ws, size_t ws_size,
                              hipStream_t stream) {
  const float* hidden = (const float*)d_in[0];
  const float* w_attn = (const float*)d_in[1];
  const float* b_attn = (const float*)d_in[2];
  const float* w_proj = (const float*)d_in[3];
  const float* b_proj = (const float*)d_in[4];

  char* ws = (char*)d_ws;
  char* dob = (char*)d_out;

  bf16* Xbf = (bf16*)ws;
  bf16* WpT = (bf16*)(ws + 33554432);
  bf16* QKV = (bf16*)dob;
  bf16* WaT = (bf16*)(dob + 37748736);
  bf16* Vt = (bf16*)(dob + 50331648);

  cast_bf16_kernel<<<(T_ * HID_) / 8 / 256, 256, 0, stream>>>(hidden, Xbf, (T_ * HID_) / 8);
  transpose_cast_kernel<<<dim3(NQKV_ / 32, HID_ / 32), 256, 0, stream>>>(w_attn, WaT, HID_, NQKV_);
  transpose_cast_kernel<<<dim3(HID_ / 32, HID_ / 32), 256, 0, stream>>>(w_proj, WpT, HID_, HID_);

  gemm_kernel<false><<<dim3(NQKV_ / 128, T_ / 128), 256, 0, stream>>>(
      Xbf, WaT, b_attn, QKV, T_, NQKV_, HID_);

  transpose_v_kernel<<<dim3(S_ / 64, D_ / 64, B_), 256, 0, stream>>>(QKV, Vt);

  attn_kernel<<<dim3(4, H_, B_), 256, 0, stream>>>(QKV, Vt, Xbf);

  gemm_kernel<true><<<dim3(HID_ / 128, T_ / 128), 256, 0, stream>>>(
      Xbf, WpT, b_proj, (float*)d_out, T_, HID_, HID_);
}